// Round 1
// baseline (411.398 us; speedup 1.0000x reference)
//
#include <hip/hip_runtime.h>
#include <math.h>

// MADE autoregressive sampler, incremental-by-degree algorithm.
// B=8192, D=64, CTX=256, H=512. Hidden degrees mh = h%63+1; sorting units by
// degree makes all masks triangular, so each degree-group finalizes exactly
// when first needed. Total work ~3e9 MACs vs 3.8e11 naive.

#define Bn 8192
#define Dn 64
#define CTXn 256
#define Hn 512
#define On 128
#define Rn 16   // batch rows per block

// prefix count of sorted units with degree < k. degrees 1..8 have 9 units,
// 9..63 have 8 units. S(64)=512.
__device__ __forceinline__ int S_of(int k) {
  if (k <= 0) return 0;
  if (k <= 9) return 9 * (k - 1);
  return 72 + 8 * (k - 9);
}

// sorted index p -> original hidden unit h, and its degree k.
__device__ __forceinline__ int perm_of(int p, int* degout) {
  int k, t;
  if (p < 72) { k = p / 9 + 1; t = p - (k - 1) * 9; }
  else        { int pp = p - 72; k = pp / 8 + 9; t = pp - (k - 9) * 8; }
  *degout = k;
  return (k - 1) + 63 * t;
}

__device__ __forceinline__ void load16(const float* src, float* dst) {
  const float4* s4 = (const float4*)src;
  float4 a = s4[0], b = s4[1], c = s4[2], d = s4[3];
  dst[0]=a.x; dst[1]=a.y; dst[2]=a.z; dst[3]=a.w;
  dst[4]=b.x; dst[5]=b.y; dst[6]=b.z; dst[7]=b.w;
  dst[8]=c.x; dst[9]=c.y; dst[10]=c.z; dst[11]=c.w;
  dst[12]=d.x; dst[13]=d.y; dst[14]=d.z; dst[15]=d.w;
}

// ---------------- prep: permuted/masked weight copies into ws ----------------
// W2t[p_in][q_out] (lane-coalesced over q), WcpT[c][p], W1c[i][p], WoT[p][o].
__global__ void prep_kernel(const float* __restrict__ W1, const float* __restrict__ Wc,
                            const float* __restrict__ W2, const float* __restrict__ Wo,
                            float* __restrict__ W2t, float* __restrict__ WcpT,
                            float* __restrict__ W1c, float* __restrict__ WoT) {
  int idx = blockIdx.x * 256 + threadIdx.x;
  if (idx < 262144) {                       // W2t: [p][q]
    int p = idx >> 9, q = idx & 511;
    int dp, dq; int hp = perm_of(p, &dp); int hq = perm_of(q, &dq);
    W2t[idx] = (dq >= dp) ? W2[hq * Hn + hp] : 0.f;   // M2: deg_out >= deg_in
  } else if (idx < 262144 + 131072) {       // WcpT: [c][p]
    int j = idx - 262144; int c = j >> 9, p = j & 511;
    int dp; int hp = perm_of(p, &dp);
    WcpT[j] = Wc[hp * CTXn + c];
  } else if (idx < 262144 + 131072 + 32768) { // W1c: [i][p]
    int j = idx - (262144 + 131072); int i = j >> 9, p = j & 511;
    int dp; int hp = perm_of(p, &dp);
    W1c[j] = (dp >= i + 1) ? W1[hp * Dn + i] : 0.f;   // M1: mh >= d+1
  } else {                                   // WoT: [p][o]
    int j = idx - (262144 + 131072 + 32768); int p = j >> 7, o = j & 127;
    int dp; int hp = perm_of(p, &dp);
    WoT[j] = (dp <= (o & 63)) ? Wo[o * Hn + hp] : 0.f; // Mo: mo > mh
  }
}

// ---------------- ctx GEMM: A1g[b][p] = context @ Wc.T (permuted) + b1 -------
__global__ __launch_bounds__(256) void ctx_gemm_kernel(
    const float* __restrict__ context, const float* __restrict__ WcpT,
    const float* __restrict__ b1, float* __restrict__ A1g) {
  __shared__ float ctxT[CTXn][Rn];  // 16 KB, transposed for float4 broadcast
  int t = threadIdx.x;
  int b0 = blockIdx.x * Rn;
  #pragma unroll
  for (int u = 0; u < Rn; ++u)
    ctxT[t][u] = context[(b0 + u) * CTXn + t];  // coalesced read
  __syncthreads();
  int q0 = t, q1 = t + 256;
  int d0, d1; int h0 = perm_of(q0, &d0); int h1 = perm_of(q1, &d1);
  float bias0 = b1[h0], bias1 = b1[h1];
  float acc0[Rn], acc1[Rn];
  #pragma unroll
  for (int r = 0; r < Rn; ++r) { acc0[r] = bias0; acc1[r] = bias1; }
  for (int c = 0; c < CTXn; ++c) {
    float w0 = WcpT[c * Hn + q0];   // coalesced, L2-resident
    float w1 = WcpT[c * Hn + q1];
    float xs[16]; load16(&ctxT[c][0], xs);  // 4x ds_read_b128, broadcast
    #pragma unroll
    for (int r = 0; r < Rn; ++r) {
      acc0[r] = fmaf(xs[r], w0, acc0[r]);
      acc1[r] = fmaf(xs[r], w1, acc1[r]);
    }
  }
  #pragma unroll
  for (int r = 0; r < Rn; ++r) {
    A1g[(b0 + r) * Hn + q0] = acc0[r];
    A1g[(b0 + r) * Hn + q1] = acc1[r];
  }
}

// ---------------- main sequential kernel ------------------------------------
__global__ __launch_bounds__(256) void made_seq_kernel(
    const float* __restrict__ A1g, const float* __restrict__ W2t,
    const float* __restrict__ W1c, const float* __restrict__ WoT,
    const float* __restrict__ b2, const float* __restrict__ bo,
    const float* __restrict__ eps, float* __restrict__ out) {
  __shared__ float h1g[9][Rn];
  __shared__ float h2g[9][Rn];
  __shared__ float oacc[Rn][On];
  __shared__ float zL[Rn][Dn];
  __shared__ float muL[Rn][Dn];
  __shared__ float scL[Rn][Dn];
  __shared__ float epsL[Rn][Dn];
  __shared__ float zcur[Rn];

  int t = threadIdx.x;
  int b0 = blockIdx.x * Rn;
  int q0 = t, q1 = t + 256;
  int dg0, dg1; int h0 = perm_of(q0, &dg0); int h1 = perm_of(q1, &dg1);

  float a1[2][Rn], a2[2][Rn];
  {
    float b20 = b2[h0], b21 = b2[h1];
    #pragma unroll
    for (int r = 0; r < Rn; ++r) {
      a1[0][r] = A1g[(b0 + r) * Hn + q0];   // coalesced
      a1[1][r] = A1g[(b0 + r) * Hn + q1];
      a2[0][r] = b20; a2[1][r] = b21;
    }
  }
  for (int idx = t; idx < Rn * On; idx += 256) oacc[idx >> 7][idx & 127] = bo[idx & 127];
  for (int idx = t; idx < Rn * Dn; idx += 256)
    epsL[idx >> 6][idx & 63] = eps[(b0 + (idx >> 6)) * Dn + (idx & 63)];
  __syncthreads();

  for (int i = 0; i < Dn; ++i) {
    int sg = S_of(i), eg = S_of(i + 1);
    int c = eg - sg;   // 0 at i=0, else 8 or 9

    // Phase A: degree-i layer-1 group finalizes -> relu -> LDS broadcast
    if (q0 >= sg && q0 < eg) {
      int p = q0 - sg;
      #pragma unroll
      for (int r = 0; r < Rn; ++r) h1g[p][r] = fmaxf(a1[0][r], 0.f);
    }
    if (q1 >= sg && q1 < eg) {
      int p = q1 - sg;
      #pragma unroll
      for (int r = 0; r < Rn; ++r) h1g[p][r] = fmaxf(a1[1][r], 0.f);
    }
    __syncthreads();

    // Phase B: rank-c update a2[q >= sg] += W2t[sg..eg)[q] * h1g
    if (c > 0 && q1 >= sg) {
      if (q0 >= sg) {
        #pragma unroll
        for (int p = 0; p < 9; ++p) {
          float wv1 = (p < c) ? W2t[(sg + p) * Hn + q1] : 0.f;
          float wv0 = (p < c) ? W2t[(sg + p) * Hn + q0] : 0.f;
          float xs[16]; load16(&h1g[p][0], xs);
          #pragma unroll
          for (int r = 0; r < Rn; ++r) {
            a2[1][r] = fmaf(wv1, xs[r], a2[1][r]);
            a2[0][r] = fmaf(wv0, xs[r], a2[0][r]);
          }
        }
      } else {
        #pragma unroll
        for (int p = 0; p < 9; ++p) {
          float wv1 = (p < c) ? W2t[(sg + p) * Hn + q1] : 0.f;
          float xs[16]; load16(&h1g[p][0], xs);
          #pragma unroll
          for (int r = 0; r < Rn; ++r) a2[1][r] = fmaf(wv1, xs[r], a2[1][r]);
        }
      }
    }

    // Phase C: degree-i layer-2 group now final -> relu -> LDS
    if (q0 >= sg && q0 < eg) {
      int p = q0 - sg;
      #pragma unroll
      for (int r = 0; r < Rn; ++r) h2g[p][r] = fmaxf(a2[0][r], 0.f);
    }
    if (q1 >= sg && q1 < eg) {
      int p = q1 - sg;
      #pragma unroll
      for (int r = 0; r < Rn; ++r) h2g[p][r] = fmaxf(a2[1][r], 0.f);
    }
    __syncthreads();

    // Phase D: o_acc[r][o] += h2g . WoT for output cols with (o&63) >= i
    if (c > 0) {
      #pragma unroll
      for (int u = 0; u < 8; ++u) {
        int idx = t + 256 * u; int r = idx >> 7; int o = idx & 127;
        if ((o & 63) >= i) {
          float acc = oacc[r][o];
          #pragma unroll
          for (int p = 0; p < 9; ++p) {
            float wv = (p < c) ? WoT[(sg + p) * On + o] : 0.f;  // coalesced over o
            acc = fmaf(h2g[p][r], wv, acc);                     // broadcast read
          }
          oacc[r][o] = acc;
        }
      }
    }
    __syncthreads();

    // Phase E: columns (i, 64+i) are final -> sample z_i
    if (t < Rn) {
      float mu = oacc[t][i];
      float pre = oacc[t][Dn + i];
      float sc = fmaxf(pre, 0.f) + log1pf(expf(-fabsf(pre)));  // softplus
      float z = mu + sc * epsL[t][i];
      zL[t][i] = z; muL[t][i] = mu; scL[t][i] = sc; zcur[t] = z;
    }
    __syncthreads();

    // Phase F: a1[q with deg > i] += z_i * W1[:,i]
    if (q1 >= eg) {
      float zs[16]; load16(&zcur[0], zs);
      float wv1 = W1c[i * Hn + q1];
      #pragma unroll
      for (int r = 0; r < Rn; ++r) a1[1][r] = fmaf(wv1, zs[r], a1[1][r]);
      if (q0 >= eg) {
        float wv0 = W1c[i * Hn + q0];
        #pragma unroll
        for (int r = 0; r < Rn; ++r) a1[0][r] = fmaf(wv0, zs[r], a1[0][r]);
      }
    }
    // no barrier needed: zcur next written after 3 barriers (next phase E)
  }

  // epilogue: coalesced writes of z, mu, scale
  for (int idx = t; idx < Rn * Dn; idx += 256) {
    int r = idx >> 6, cc = idx & 63;
    out[(b0 + r) * Dn + cc] = zL[r][cc];
    out[Bn * Dn + (b0 + r) * Dn + cc] = muL[r][cc];
    out[2 * Bn * Dn + (b0 + r) * Dn + cc] = scL[r][cc];
  }
}

extern "C" void kernel_launch(void* const* d_in, const int* in_sizes, int n_in,
                              void* d_out, int out_size, void* d_ws, size_t ws_size,
                              hipStream_t stream) {
  const float* context = (const float*)d_in[0];
  const float* eps     = (const float*)d_in[1];
  const float* W1      = (const float*)d_in[2];
  const float* b1      = (const float*)d_in[3];
  const float* Wc      = (const float*)d_in[4];
  const float* W2      = (const float*)d_in[5];
  const float* b2      = (const float*)d_in[6];
  const float* Wo      = (const float*)d_in[7];
  const float* bo      = (const float*)d_in[8];
  float* out = (float*)d_out;

  float* ws   = (float*)d_ws;
  float* A1g  = ws;                    // B*H      = 4194304 floats
  float* W2t  = A1g + (size_t)Bn * Hn; // H*H      =  262144
  float* WcpT = W2t + Hn * Hn;         // CTX*H    =  131072
  float* W1c  = WcpT + CTXn * Hn;      // D*H      =   32768
  float* WoT  = W1c + Dn * Hn;         // H*2D     =   65536
  // total ws use: ~18.7 MB

  prep_kernel<<<1920, 256, 0, stream>>>(W1, Wc, W2, Wo, W2t, WcpT, W1c, WoT);
  ctx_gemm_kernel<<<Bn / Rn, 256, 0, stream>>>(context, WcpT, b1, A1g);
  made_seq_kernel<<<Bn / Rn, 256, 0, stream>>>(A1g, W2t, W1c, WoT, b2, bo, eps, out);
}

// Round 2
// 370.478 us; speedup vs baseline: 1.1105x; 1.1105x over previous
//
#include <hip/hip_runtime.h>
#include <math.h>

// MADE autoregressive sampler, incremental-by-degree algorithm, v2.
// B=8192, D=64, CTX=256, H=512. Units sorted by degree (mh = h%63+1) make all
// masks triangular; degree-i groups finalize exactly at step i.
// v2: oacc in registers (owner-thread per (row, colpair)) -> 3 barriers/iter,
// Rn=8 -> 1024 blocks (4/CU), fused ctx-GEMM prologue, fast softplus.

#define Bn 8192
#define Dn 64
#define CTXn 256
#define Hn 512
#define On 128
#define Rn 8   // batch rows per block

// prefix count of sorted units with degree < k. degrees 1..8 have 9 units,
// 9..63 have 8 units. S(64)=512.
__device__ __forceinline__ int S_of(int k) {
  if (k <= 0) return 0;
  if (k <= 9) return 9 * (k - 1);
  return 72 + 8 * (k - 9);
}

// sorted index p -> original hidden unit h, and its degree k.
__device__ __forceinline__ int perm_of(int p, int* degout) {
  int k, t;
  if (p < 72) { k = p / 9 + 1; t = p - (k - 1) * 9; }
  else        { int pp = p - 72; k = pp / 8 + 9; t = pp - (k - 9) * 8; }
  *degout = k;
  return (k - 1) + 63 * t;
}

// ---------------- prep: permuted/masked weight copies into ws ----------------
// W2t[p_in][q_out] (lane-coalesced over q), WcpT[c][p], W1c[i][p], WoT[p][o].
__global__ void prep_kernel(const float* __restrict__ W1, const float* __restrict__ Wc,
                            const float* __restrict__ W2, const float* __restrict__ Wo,
                            float* __restrict__ W2t, float* __restrict__ WcpT,
                            float* __restrict__ W1c, float* __restrict__ WoT) {
  int idx = blockIdx.x * 256 + threadIdx.x;
  if (idx < 262144) {                       // W2t: [p][q]
    int p = idx >> 9, q = idx & 511;
    int dp, dq; int hp = perm_of(p, &dp); int hq = perm_of(q, &dq);
    W2t[idx] = (dq >= dp) ? W2[hq * Hn + hp] : 0.f;   // M2: deg_out >= deg_in
  } else if (idx < 262144 + 131072) {       // WcpT: [c][p]
    int j = idx - 262144; int c = j >> 9, p = j & 511;
    int dp; int hp = perm_of(p, &dp);
    WcpT[j] = Wc[hp * CTXn + c];
  } else if (idx < 262144 + 131072 + 32768) { // W1c: [i][p]
    int j = idx - (262144 + 131072); int i = j >> 9, p = j & 511;
    int dp; int hp = perm_of(p, &dp);
    W1c[j] = (dp >= i + 1) ? W1[hp * Dn + i] : 0.f;   // M1: mh >= d+1
  } else {                                   // WoT: [p][o]
    int j = idx - (262144 + 131072 + 32768); int p = j >> 7, o = j & 127;
    int dp; int hp = perm_of(p, &dp);
    WoT[j] = (dp <= (o & 63)) ? Wo[o * Hn + hp] : 0.f; // Mo: mo > mh
  }
}

// ---------------- main fused kernel ------------------------------------------
__global__ __launch_bounds__(256, 4) void made_seq_kernel(
    const float* __restrict__ context, const float* __restrict__ WcpT,
    const float* __restrict__ b1,
    const float* __restrict__ W2t, const float* __restrict__ W1c,
    const float* __restrict__ WoT, const float* __restrict__ b2,
    const float* __restrict__ bo, const float* __restrict__ eps,
    float* __restrict__ out) {
  __shared__ float ctxR[8][264];   // [r][c], padded: writes conflict-free,
                                   // rows 16B-aligned (264*4 % 16 == 0)
  __shared__ float h1g[9][Rn];
  __shared__ float h2g[9][Rn];
  __shared__ float zL[Rn][Dn];
  __shared__ float muL[Rn][Dn];
  __shared__ float scL[Rn][Dn];
  __shared__ float epsL[Rn][Dn];
  __shared__ float zcur[Rn];

  int t = threadIdx.x;
  int b0 = blockIdx.x * Rn;
  int q0 = t, q1 = t + 256;                  // sorted hidden units owned
  int j  = t & 63, rg = t >> 6;              // colpair owner: cols {j, j+64},
  int rlo = 2 * rg, rhi = rlo + 1;           // rows rlo, rhi

  // ---- stage context (transposed) + eps ----
  #pragma unroll
  for (int r = 0; r < Rn; ++r)
    ctxR[r][t] = context[(b0 + r) * CTXn + t];            // coalesced
  for (int idx = t; idx < Rn * Dn; idx += 256)
    epsL[idx >> 6][idx & 63] = eps[(b0 + (idx >> 6)) * Dn + (idx & 63)];
  __syncthreads();

  // ---- fused ctx GEMM: a1[q] = b1[h] + ctx . WcpT[:,q] ----
  int dg0, dg1; int h0 = perm_of(q0, &dg0); int h1 = perm_of(q1, &dg1);
  float a1_0[Rn], a1_1[Rn];
  {
    float bias0 = b1[h0], bias1 = b1[h1];
    #pragma unroll
    for (int r = 0; r < Rn; ++r) { a1_0[r] = bias0; a1_1[r] = bias1; }
  }
  for (int c4 = 0; c4 < CTXn / 4; ++c4) {
    float xr[Rn][4];
    #pragma unroll
    for (int r = 0; r < Rn; ++r) {
      float4 x = *(const float4*)&ctxR[r][4 * c4];
      xr[r][0] = x.x; xr[r][1] = x.y; xr[r][2] = x.z; xr[r][3] = x.w;
    }
    #pragma unroll
    for (int k = 0; k < 4; ++k) {
      float w0 = WcpT[(4 * c4 + k) * Hn + q0];   // coalesced, L2-resident
      float w1 = WcpT[(4 * c4 + k) * Hn + q1];
      #pragma unroll
      for (int r = 0; r < Rn; ++r) {
        a1_0[r] = fmaf(xr[r][k], w0, a1_0[r]);
        a1_1[r] = fmaf(xr[r][k], w1, a1_1[r]);
      }
    }
  }

  // ---- init a2 (bias) and register oacc ----
  float a2_0[Rn], a2_1[Rn];
  {
    float b20 = b2[h0], b21 = b2[h1];
    #pragma unroll
    for (int r = 0; r < Rn; ++r) { a2_0[r] = b20; a2_1[r] = b21; }
  }
  float oc00 = bo[j], oc01 = bo[j + 64];   // row rlo, cols j / j+64
  float oc10 = oc00,  oc11 = oc01;         // row rhi (same bias)

  // ---- sequential loop over output dims ----
  for (int i = 0; i < Dn; ++i) {
    int sg = S_of(i), eg = S_of(i + 1);
    int c = eg - sg;   // 0 at i=0, else 8 or 9

    // Phase A: degree-i layer-1 group finalizes -> relu -> LDS broadcast
    if (q0 >= sg && q0 < eg) {
      int p = q0 - sg;
      #pragma unroll
      for (int r = 0; r < Rn; ++r) h1g[p][r] = fmaxf(a1_0[r], 0.f);
    }
    if (q1 >= sg && q1 < eg) {
      int p = q1 - sg;
      #pragma unroll
      for (int r = 0; r < Rn; ++r) h1g[p][r] = fmaxf(a1_1[r], 0.f);
    }
    __syncthreads();   // bar 1

    // Phase B: rank-c update a2[q >= sg] += W2t[sg+p][q] * h1g[p][:]
    if (c) {
      bool u0 = (q0 >= sg), u1 = (q1 >= sg);
      #pragma unroll
      for (int p = 0; p < 9; ++p) {
        float wv0 = (p < c && u0) ? W2t[(sg + p) * Hn + q0] : 0.f;
        float wv1 = (p < c && u1) ? W2t[(sg + p) * Hn + q1] : 0.f;
        float4 xa = *(const float4*)&h1g[p][0];   // broadcast
        float4 xb = *(const float4*)&h1g[p][4];
        float xs[8] = {xa.x, xa.y, xa.z, xa.w, xb.x, xb.y, xb.z, xb.w};
        #pragma unroll
        for (int r = 0; r < Rn; ++r) {
          a2_0[r] = fmaf(wv0, xs[r], a2_0[r]);
          a2_1[r] = fmaf(wv1, xs[r], a2_1[r]);
        }
      }
      // Phase C: degree-i layer-2 group now final -> relu -> LDS
      if (q0 >= sg && q0 < eg) {
        int p = q0 - sg;
        #pragma unroll
        for (int r = 0; r < Rn; ++r) h2g[p][r] = fmaxf(a2_0[r], 0.f);
      }
      if (q1 >= sg && q1 < eg) {
        int p = q1 - sg;
        #pragma unroll
        for (int r = 0; r < Rn; ++r) h2g[p][r] = fmaxf(a2_1[r], 0.f);
      }
    }
    __syncthreads();   // bar 2

    // Phase D: register oacc += h2g . WoT for this thread's (rows, colpair)
    if (c && j >= i) {
      #pragma unroll
      for (int p = 0; p < 9; ++p) {
        float w0 = (p < c) ? WoT[(sg + p) * On + j] : 0.f;       // coalesced
        float w1 = (p < c) ? WoT[(sg + p) * On + j + 64] : 0.f;
        float hlo = h2g[p][rlo], hhi = h2g[p][rhi];               // broadcast
        oc00 = fmaf(hlo, w0, oc00); oc01 = fmaf(hlo, w1, oc01);
        oc10 = fmaf(hhi, w0, oc10); oc11 = fmaf(hhi, w1, oc11);
      }
    }
    // Phase E: this thread owns final cols (i, 64+i) for its 2 rows
    if (j == i) {
      float mu0 = oc00, pre0 = oc01;
      float mu1 = oc10, pre1 = oc11;
      float sc0 = fmaxf(pre0, 0.f) + __logf(1.f + __expf(-fabsf(pre0)));
      float sc1 = fmaxf(pre1, 0.f) + __logf(1.f + __expf(-fabsf(pre1)));
      float z0 = mu0 + sc0 * epsL[rlo][i];
      float z1 = mu1 + sc1 * epsL[rhi][i];
      zcur[rlo] = z0; zcur[rhi] = z1;
      zL[rlo][i] = z0; muL[rlo][i] = mu0; scL[rlo][i] = sc0;
      zL[rhi][i] = z1; muL[rhi][i] = mu1; scL[rhi][i] = sc1;
    }
    __syncthreads();   // bar 3

    // Phase F: a1[q with deg > i] += z_i * W1c[i][q]
    {
      float4 za = *(const float4*)&zcur[0];
      float4 zb = *(const float4*)&zcur[4];
      float zs[8] = {za.x, za.y, za.z, za.w, zb.x, zb.y, zb.z, zb.w};
      if (q1 >= eg) {
        float wv1 = W1c[i * Hn + q1];
        #pragma unroll
        for (int r = 0; r < Rn; ++r) a1_1[r] = fmaf(wv1, zs[r], a1_1[r]);
        if (q0 >= eg) {
          float wv0 = W1c[i * Hn + q0];
          #pragma unroll
          for (int r = 0; r < Rn; ++r) a1_0[r] = fmaf(wv0, zs[r], a1_0[r]);
        }
      }
    }
    // no barrier: next write to zcur/h1g is 2+ barriers away
  }

  // epilogue: coalesced writes of z, mu, scale
  for (int idx = t; idx < Rn * Dn; idx += 256) {
    int r = idx >> 6, cc = idx & 63;
    out[(b0 + r) * Dn + cc] = zL[r][cc];
    out[Bn * Dn + (b0 + r) * Dn + cc] = muL[r][cc];
    out[2 * Bn * Dn + (b0 + r) * Dn + cc] = scL[r][cc];
  }
}

extern "C" void kernel_launch(void* const* d_in, const int* in_sizes, int n_in,
                              void* d_out, int out_size, void* d_ws, size_t ws_size,
                              hipStream_t stream) {
  const float* context = (const float*)d_in[0];
  const float* eps     = (const float*)d_in[1];
  const float* W1      = (const float*)d_in[2];
  const float* b1      = (const float*)d_in[3];
  const float* Wc      = (const float*)d_in[4];
  const float* W2      = (const float*)d_in[5];
  const float* b2      = (const float*)d_in[6];
  const float* Wo      = (const float*)d_in[7];
  const float* bo      = (const float*)d_in[8];
  float* out = (float*)d_out;

  float* ws   = (float*)d_ws;
  float* W2t  = ws;                    // H*H   = 262144 floats
  float* WcpT = W2t + Hn * Hn;         // CTX*H = 131072
  float* W1c  = WcpT + CTXn * Hn;      // D*H   =  32768
  float* WoT  = W1c + Dn * Hn;         // H*2D  =  65536
  // total ws use: ~1.9 MB (L2-resident)

  prep_kernel<<<1920, 256, 0, stream>>>(W1, Wc, W2, Wo, W2t, WcpT, W1c, WoT);
  made_seq_kernel<<<Bn / Rn, 256, 0, stream>>>(context, WcpT, b1, W2t, W1c,
                                               WoT, b2, bo, eps, out);
}